// Round 6
// baseline (56.226 us; speedup 1.0000x reference)
//
#include <hip/hip_runtime.h>

// Problem constants (match reference)
#define BATCH 256
#define PTS   4096
#define HH    512
#define WW    512

#define ROWS_PER_TILE 16
#define TILES (HH / ROWS_PER_TILE)       // 32 tiles per batch
#define TILE_ELEMS (ROWS_PER_TILE * WW)  // 8192 floats = 32 KB LDS

typedef float f32x4 __attribute__((ext_vector_type(4)));

// ws layout:
//   entries: BATCH*PTS uint2 (packed pos, val bits)  = 8 MB   @ ws + 0
//   counts : BATCH*TILES u32                          = 32 KB  @ ws + 8 MB
//   offsets: BATCH*TILES u32                          = 32 KB  @ ws + 8 MB + 32 KB
#define ENTRIES_BYTES ((size_t)BATCH * PTS * 8)

// K1: one block per batch. Scan the point list ONCE, build a per-batch
// CSR binned by 16-row tile. No global atomics; exact counts via LDS.
__global__ __launch_bounds__(1024) void bin_kernel(
        const int* __restrict__ indices,      // [B, P, 2] int32
        const int* __restrict__ num_valid,    // [B] int32
        const float* __restrict__ feats,      // [B, P, 1] f32
        uint2* __restrict__ entries,          // [B, P]
        unsigned* __restrict__ counts,        // [B, TILES]
        unsigned* __restrict__ offsets)       // [B, TILES]
{
    __shared__ unsigned cnt[TILES];
    __shared__ unsigned cur[TILES];

    int b = blockIdx.x;
    int tidx = threadIdx.x;
    if (tidx < TILES) cnt[tidx] = 0;
    int nv = num_valid[b];
    __syncthreads();

    const int2* idx2 = reinterpret_cast<const int2*>(indices) + (size_t)b * PTS;

    // Pass A: count points per tile (LDS atomics, 32 counters).
    for (int p = tidx; p < nv; p += 1024)
        atomicAdd(&cnt[((unsigned)idx2[p].x) >> 4], 1u);
    __syncthreads();

    // Exclusive prefix (32 elements — serial by thread 0 is negligible).
    if (tidx == 0) {
        unsigned run = 0;
        for (int i = 0; i < TILES; ++i) { cur[i] = run; run += cnt[i]; }
    }
    __syncthreads();

    if (tidx < TILES) {
        counts[b * TILES + tidx]  = cnt[tidx];
        offsets[b * TILES + tidx] = cur[tidx];
    }
    __syncthreads();   // offsets captured before pass B mutates cur[]

    // Pass B: re-scan (L1/L2-hot) and write entries at exact positions.
    const float* fb = feats + (size_t)b * PTS;
    uint2* eb = entries + (size_t)b * PTS;
    for (int p = tidx; p < nv; p += 1024) {
        int2 ij = idx2[p];
        float v = fb[p];
        unsigned bin = ((unsigned)ij.x) >> 4;
        unsigned pos = atomicAdd(&cur[bin], 1u);   // absolute within batch
        eb[pos] = make_uint2((unsigned)((ij.x & (ROWS_PER_TILE - 1)) * WW + ij.y),
                             __float_as_uint(v));
    }
}

// K2: one block per (batch, tile). Zero 32 KB LDS, apply the tile's bin
// (~128 entries, contiguous), write the tile exactly once, non-temporal.
// Pre-store phase is ~1% of block time -> store-stream dominated.
__global__ __launch_bounds__(256) void tile_write_kernel(
        const uint2* __restrict__ entries,
        const unsigned* __restrict__ counts,
        const unsigned* __restrict__ offsets,
        float* __restrict__ out)              // [B, H, W] f32
{
    __shared__ float tile[TILE_ELEMS];

    // XCD-aware remap: each XCD owns 32 whole batches (entries/counts
    // stay in one L2).
    int i = blockIdx.x;                       // [0, 8192)
    int xcd  = i & 7;
    int slot = i >> 3;                        // [0, 1024)
    int b = xcd * (BATCH / 8) + (slot >> 5);
    int t = slot & (TILES - 1);
    int tidx = threadIdx.x;

    f32x4* tile4 = reinterpret_cast<f32x4*>(tile);
    #pragma unroll
    for (int k = tidx; k < TILE_ELEMS / 4; k += 256)
        tile4[k] = (f32x4){0.f, 0.f, 0.f, 0.f};

    unsigned n   = counts[b * TILES + t];
    unsigned off = offsets[b * TILES + t];
    __syncthreads();

    const uint2* eb = entries + (size_t)b * PTS + off;
    for (unsigned e = tidx; e < n; e += 256) {
        uint2 ent = eb[e];
        atomicAdd(&tile[ent.x], __uint_as_float(ent.y));
    }
    __syncthreads();

    float* ob = out + (size_t)b * (HH * WW) + (size_t)t * TILE_ELEMS;
    f32x4* dst = reinterpret_cast<f32x4*>(ob);
    #pragma unroll
    for (int k = tidx; k < TILE_ELEMS / 4; k += 256)
        __builtin_nontemporal_store(tile4[k], dst + k);
}

extern "C" void kernel_launch(void* const* d_in, const int* in_sizes, int n_in,
                              void* d_out, int out_size, void* d_ws, size_t ws_size,
                              hipStream_t stream) {
    const int*   indices   = (const int*)d_in[0];
    const int*   num_valid = (const int*)d_in[1];
    const float* feats     = (const float*)d_in[2];
    float*       out       = (float*)d_out;

    uint2*    entries = (uint2*)d_ws;
    unsigned* counts  = (unsigned*)((char*)d_ws + ENTRIES_BYTES);
    unsigned* offsets = counts + BATCH * TILES;

    bin_kernel<<<BATCH, 1024, 0, stream>>>(indices, num_valid, feats,
                                           entries, counts, offsets);
    tile_write_kernel<<<BATCH * TILES, 256, 0, stream>>>(entries, counts,
                                                         offsets, out);
}